// Round 4
// baseline (91.346 us; speedup 1.0000x reference)
//
#include <hip/hip_runtime.h>
#include <math.h>

#define BB 16
#define TT 8
#define CC 64
#define PP 2048
#define NROWS 8192
#define RPB 4                            // rows per block
#define NBLK (NROWS / RPB)               // 2048 blocks
#define TOTAL_INV (1.0f / 16777216.0f)   // 1 / (B*T*C*P)

// ---------------------------------------------------------------------------
// Async global->LDS staging (width 16). LDS dest = wave-uniform base + lane*16.
// ---------------------------------------------------------------------------
typedef __attribute__((address_space(1))) const void* as1_cvoid;
typedef __attribute__((address_space(3))) void* as3_void;

__device__ __forceinline__ void stage16(const float* g, float* l) {
    __builtin_amdgcn_global_load_lds((as1_cvoid)g, (as3_void)l, 16, 0, 0);
}

// Stage the 3 source rows for one output row: 6 global_load_lds per thread.
// Wave w owns segments w and w+4 (256 floats each) of every row.
__device__ __forceinline__ void stage_rows(float (*dst)[PP], const float* x,
                                           size_t a0, size_t a1, size_t a2,
                                           int wave, int lane)
{
    #pragma unroll
    for (int s = 0; s < 2; ++s) {
        const int seg = wave + s * 4;
        const int fo  = seg * 256 + lane * 4;
        stage16(x + a0 + fo, &dst[0][seg * 256]);
        stage16(x + a1 + fo, &dst[1][seg * 256]);
        stage16(x + a2 + fo, &dst[2][seg * 256]);
    }
}

__device__ __forceinline__ size_t src_of(const int* pB, const int* pT,
                                         const int* pC, int b, int t, int c) {
    return ((size_t)((pB[b] * TT + pT[t]) * CC + pC[c])) * PP;
}

// ---------------------------------------------------------------------------
// Mask-dtype classifier (16 KiB scan) — proven in round 2 (mode detection).
// ---------------------------------------------------------------------------
__global__ __launch_bounds__(256) void mask_classify_kernel(
    const unsigned char* __restrict__ mask, int* __restrict__ flag)
{
    __shared__ int sc1, sc3f;
    if (threadIdx.x == 0) { sc1 = 0; sc3f = 0; }
    __syncthreads();
    int c1 = 0, c3f = 0;
    const uint4* m4 = (const uint4*)mask;
    for (int i = threadIdx.x; i < 1024; i += 256) {
        const uint4 v = m4[i];
        const unsigned int w[4] = {v.x, v.y, v.z, v.w};
        #pragma unroll
        for (int j = 0; j < 4; ++j) {
            #pragma unroll
            for (int bt = 0; bt < 4; ++bt) {
                const unsigned int byte = (w[j] >> (8 * bt)) & 0xffu;
                c1  += (byte == 0x01u);
                c3f += (byte == 0x3fu);
            }
        }
    }
    atomicAdd(&sc1, c1);
    atomicAdd(&sc3f, c3f);
    __syncthreads();
    if (threadIdx.x == 0) {
        int f;
        if      (sc1  > 1000) f = 0;   // u8 bool
        else if (sc3f >  600) f = 1;   // bf16
        else if (sc3f >  200) f = 2;   // f32
        else if (sc1  >  200) f = 3;   // i32
        else                  f = 0;
        *flag = f;
    }
}

template <int MODE>
__device__ __forceinline__ void mask_load(const unsigned char* __restrict__ mask,
                                          size_t idx, float mf[4])
{
    if (MODE == 0) {
        const unsigned int mv = *(const unsigned int*)(mask + idx);
        #pragma unroll
        for (int k = 0; k < 4; ++k) mf[k] = ((mv >> (8 * k)) & 0xffu) ? 1.0f : 0.0f;
    } else if (MODE == 1) {
        const ushort4 mv = *(const ushort4*)((const unsigned short*)mask + idx);
        mf[0] = mv.x ? 1.0f : 0.0f; mf[1] = mv.y ? 1.0f : 0.0f;
        mf[2] = mv.z ? 1.0f : 0.0f; mf[3] = mv.w ? 1.0f : 0.0f;
    } else if (MODE == 2) {
        const float4 mv = *(const float4*)((const float*)mask + idx);
        mf[0] = mv.x != 0.f ? 1.0f : 0.0f; mf[1] = mv.y != 0.f ? 1.0f : 0.0f;
        mf[2] = mv.z != 0.f ? 1.0f : 0.0f; mf[3] = mv.w != 0.f ? 1.0f : 0.0f;
    } else {
        const int4 mv = *(const int4*)((const int*)mask + idx);
        mf[0] = mv.x ? 1.0f : 0.0f; mf[1] = mv.y ? 1.0f : 0.0f;
        mf[2] = mv.z ? 1.0f : 0.0f; mf[3] = mv.w ? 1.0f : 0.0f;
    }
}

// ---------------------------------------------------------------------------
// Pipelined block body: RPB rows, double-buffered staging, counted vmcnt,
// raw barriers (never drain in-flight next-row staging).
// ---------------------------------------------------------------------------
template <int MODE>
__device__ __forceinline__ void block_body(
    const float* __restrict__ x, const float* __restrict__ attn,
    const float* __restrict__ noise, const unsigned char* __restrict__ mask,
    const int* __restrict__ pP1, const int* __restrict__ pP2,
    const int* __restrict__ pP3,
    float (*sbuf)[3][PP],
    const size_t* sA, const size_t* sB, const size_t* sC,
    int r0, int tid, int wave, int lane,
    float& s0, float& s1, float& s2, float& s3)
{
    // Prologue: stage row r0 into buffer 0 (6 VMEM in flight).
    stage_rows(sbuf[0], x, sA[0], sB[0], sC[0], wave, lane);

    #pragma unroll
    for (int i = 0; i < RPB; ++i) {
        const size_t rowbase = (size_t)(r0 + i) * PP;
        const int p0 = tid << 2;
        const int p1 = 1024 + (tid << 2);

        // --- A: streaming loads for row i (13 VMEM -> VGPR) ---
        const float4 xv0 = *(const float4*)(x + rowbase + p0);
        const float4 xv1 = *(const float4*)(x + rowbase + p1);
        const float4 av0 = *(const float4*)(attn + rowbase + p0);
        const float4 av1 = *(const float4*)(attn + rowbase + p1);
        const float4 nv0 = *(const float4*)(noise + rowbase + p0);
        const float4 nv1 = *(const float4*)(noise + rowbase + p1);
        const int4 q10 = *(const int4*)(pP1 + p0);
        const int4 q11 = *(const int4*)(pP1 + p1);
        const int4 q20 = *(const int4*)(pP2 + p0);
        const int4 q21 = *(const int4*)(pP2 + p1);
        const int4 q30 = *(const int4*)(pP3 + p0);
        const int4 q31 = *(const int4*)(pP3 + p1);
        float mf0[4], mf1[4];
        mask_load<MODE>(mask, rowbase + p0, mf0);
        mask_load<MODE>(mask, rowbase + p1, mf1);
        __builtin_amdgcn_sched_barrier(0);

        // --- B: stage row i+1 into the other buffer (6 VMEM, stays in flight
        //        across the barrier — this is the pipeline) ---
        if (i + 1 < RPB)
            stage_rows(sbuf[(i + 1) & 1], x, sA[i + 1], sB[i + 1], sC[i + 1],
                       wave, lane);
        __builtin_amdgcn_sched_barrier(0);

        // --- D: pos term (LDS-independent; overlaps latency) ---
        const float as0[4] = {av0.x, av0.y, av0.z, av0.w};
        const float as1v[4] = {av1.x, av1.y, av1.z, av1.w};
        {
            const float ns0[4] = {nv0.x, nv0.y, nv0.z, nv0.w};
            const float ns1[4] = {nv1.x, nv1.y, nv1.z, nv1.w};
            #pragma unroll
            for (int k = 0; k < 4; ++k) {
                const float d0a = ns0[k] * mf0[k];
                s0 += as0[k] * d0a * d0a;
                const float d0b = ns1[k] * mf1[k];
                s0 += as1v[k] * d0b * d0b;
            }
        }

        // --- E: wait own row-i staging (allow 6 newer next-row stages in
        //        flight); rule-18 fence; then cross-wave barrier ---
        asm volatile("s_waitcnt vmcnt(6)" ::: "memory");
        __builtin_amdgcn_sched_barrier(0);
        __builtin_amdgcn_s_barrier();

        // --- G: LDS gathers + neg terms ---
        {
            const float* l0 = sbuf[i & 1][0];
            const float* l1 = sbuf[i & 1][1];
            const float* l2 = sbuf[i & 1][2];
            const float xs0[4] = {xv0.x, xv0.y, xv0.z, xv0.w};
            const float xs1[4] = {xv1.x, xv1.y, xv1.z, xv1.w};
            const int q1s0[4] = {q10.x, q10.y, q10.z, q10.w};
            const int q1s1[4] = {q11.x, q11.y, q11.z, q11.w};
            const int q2s0[4] = {q20.x, q20.y, q20.z, q20.w};
            const int q2s1[4] = {q21.x, q21.y, q21.z, q21.w};
            const int q3s0[4] = {q30.x, q30.y, q30.z, q30.w};
            const int q3s1[4] = {q31.x, q31.y, q31.z, q31.w};
            #pragma unroll
            for (int k = 0; k < 4; ++k) {
                const float d1a = xs0[k] - l0[q1s0[k]];
                s1 += as0[k] * d1a * d1a;
                const float d2a = xs0[k] - l1[q2s0[k]];
                s2 += as0[k] * d2a * d2a;
                const float d3a = xs0[k] - l2[q3s0[k]];
                s3 += as0[k] * d3a * d3a;
                const float d1b = xs1[k] - l0[q1s1[k]];
                s1 += as1v[k] * d1b * d1b;
                const float d2b = xs1[k] - l1[q2s1[k]];
                s2 += as1v[k] * d2b * d2b;
                const float d3b = xs1[k] - l2[q3s1[k]];
                s3 += as1v[k] * d3b * d3b;
            }
        }
        // All gather values consumed above -> this wave's ds_reads retired.
        // Barrier: nobody overwrites buf[i&1] until everyone is done reading.
        __builtin_amdgcn_s_barrier();
        __builtin_amdgcn_sched_barrier(0);
    }
}

__global__ __launch_bounds__(256, 3) void attn_loss_row_kernel(
    const float* __restrict__ x, const float* __restrict__ attn,
    const float* __restrict__ noise, const unsigned char* __restrict__ mask,
    const int* __restrict__ pB1, const int* __restrict__ pT1,
    const int* __restrict__ pC1, const int* __restrict__ pP1,
    const int* __restrict__ pB2, const int* __restrict__ pT2,
    const int* __restrict__ pC2, const int* __restrict__ pP2,
    const int* __restrict__ pB3, const int* __restrict__ pT3,
    const int* __restrict__ pC3, const int* __restrict__ pP3,
    const int* __restrict__ mask_flag,
    float4* __restrict__ partial)
{
    __shared__ float sbuf[2][3][PP];   // 48 KiB: double-buffered 3 source rows
    __shared__ float red[4][4];

    const int tid  = threadIdx.x;
    const int wave = tid >> 6;
    const int lane = tid & 63;
    const int r0   = blockIdx.x * RPB;

    // Precompute all source-row bases (SGPR, s_loads hoisted to block front).
    size_t sA[RPB], sB[RPB], sC[RPB];
    #pragma unroll
    for (int i = 0; i < RPB; ++i) {
        const int r = r0 + i;
        const int b = r / (TT * CC);
        const int t = (r / CC) % TT;
        const int c = r % CC;
        sA[i] = src_of(pB1, pT1, pC1, b, t, c);
        sB[i] = src_of(pB2, pT2, pC2, b, t, c);
        sC[i] = src_of(pB3, pT3, pC3, b, t, c);
    }

    float s0 = 0.f, s1 = 0.f, s2 = 0.f, s3 = 0.f;

    const int f = *mask_flag;  // grid-uniform
    switch (f) {
        case 1:  block_body<1>(x, attn, noise, mask, pP1, pP2, pP3, sbuf,
                               sA, sB, sC, r0, tid, wave, lane, s0, s1, s2, s3); break;
        case 2:  block_body<2>(x, attn, noise, mask, pP1, pP2, pP3, sbuf,
                               sA, sB, sC, r0, tid, wave, lane, s0, s1, s2, s3); break;
        case 3:  block_body<3>(x, attn, noise, mask, pP1, pP2, pP3, sbuf,
                               sA, sB, sC, r0, tid, wave, lane, s0, s1, s2, s3); break;
        default: block_body<0>(x, attn, noise, mask, pP1, pP2, pP3, sbuf,
                               sA, sB, sC, r0, tid, wave, lane, s0, s1, s2, s3); break;
    }

    #pragma unroll
    for (int off = 32; off; off >>= 1) {
        s0 += __shfl_down(s0, off, 64);
        s1 += __shfl_down(s1, off, 64);
        s2 += __shfl_down(s2, off, 64);
        s3 += __shfl_down(s3, off, 64);
    }
    if (lane == 0) {
        red[0][wave] = s0; red[1][wave] = s1;
        red[2][wave] = s2; red[3][wave] = s3;
    }
    __syncthreads();
    if (tid == 0) {
        float4 out;
        out.x = red[0][0] + red[0][1] + red[0][2] + red[0][3];
        out.y = red[1][0] + red[1][1] + red[1][2] + red[1][3];
        out.z = red[2][0] + red[2][1] + red[2][2] + red[2][3];
        out.w = red[3][0] + red[3][1] + red[3][2] + red[3][3];
        partial[blockIdx.x] = out;
    }
}

__global__ __launch_bounds__(1024) void attn_loss_final_kernel(
    const float4* __restrict__ partial, float* __restrict__ out)
{
    const int tid = threadIdx.x;
    float s0 = 0.f, s1 = 0.f, s2 = 0.f, s3 = 0.f;
    for (int i = tid; i < NBLK; i += 1024) {
        const float4 v = partial[i];
        s0 += v.x; s1 += v.y; s2 += v.z; s3 += v.w;
    }
    #pragma unroll
    for (int off = 32; off; off >>= 1) {
        s0 += __shfl_down(s0, off, 64);
        s1 += __shfl_down(s1, off, 64);
        s2 += __shfl_down(s2, off, 64);
        s3 += __shfl_down(s3, off, 64);
    }
    __shared__ float red[4][16];
    const int wave = tid >> 6;
    const int lane = tid & 63;
    if (lane == 0) {
        red[0][wave] = s0; red[1][wave] = s1;
        red[2][wave] = s2; red[3][wave] = s3;
    }
    __syncthreads();
    if (tid == 0) {
        float lp = 0.f, l1 = 0.f, l2 = 0.f, l3 = 0.f;
        #pragma unroll
        for (int w = 0; w < 16; ++w) {
            lp += red[0][w]; l1 += red[1][w];
            l2 += red[2][w]; l3 += red[3][w];
        }
        lp *= TOTAL_INV; l1 *= TOTAL_INV; l2 *= TOTAL_INV; l3 *= TOTAL_INV;
        const float m   = fmaxf(l1, fmaxf(l2, l3));
        const float lse = m + logf(expf(l1 - m) + expf(l2 - m) + expf(l3 - m));
        out[0] = lse - lp;
    }
}

extern "C" void kernel_launch(void* const* d_in, const int* in_sizes, int n_in,
                              void* d_out, int out_size, void* d_ws, size_t ws_size,
                              hipStream_t stream) {
    const float* x            = (const float*)d_in[0];
    const float* attn         = (const float*)d_in[1];
    const float* noise        = (const float*)d_in[2];
    const unsigned char* mask = (const unsigned char*)d_in[3];
    const int* pB1 = (const int*)d_in[4];
    const int* pT1 = (const int*)d_in[5];
    const int* pC1 = (const int*)d_in[6];
    const int* pP1 = (const int*)d_in[7];
    const int* pB2 = (const int*)d_in[8];
    const int* pT2 = (const int*)d_in[9];
    const int* pC2 = (const int*)d_in[10];
    const int* pP2 = (const int*)d_in[11];
    const int* pB3 = (const int*)d_in[12];
    const int* pT3 = (const int*)d_in[13];
    const int* pC3 = (const int*)d_in[14];
    const int* pP3 = (const int*)d_in[15];

    float4* partial = (float4*)d_ws;                    // 32 KiB
    int* mask_flag  = (int*)((char*)d_ws + NBLK * 16);  // 4 B after partials

    mask_classify_kernel<<<1, 256, 0, stream>>>(mask, mask_flag);
    attn_loss_row_kernel<<<NBLK, 256, 0, stream>>>(
        x, attn, noise, mask,
        pB1, pT1, pC1, pP1, pB2, pT2, pC2, pP2, pB3, pT3, pC3, pP3,
        mask_flag, partial);
    attn_loss_final_kernel<<<1, 1024, 0, stream>>>(partial, (float*)d_out);
}

// Round 5
// 85.694 us; speedup vs baseline: 1.0660x; 1.0660x over previous
//
#include <hip/hip_runtime.h>
#include <math.h>

#define BB 16
#define TT 8
#define CC 64
#define PP 2048
#define NROWS 8192
#define RPB 4                            // rows per block (grid-stride-style)
#define NBLK (NROWS / RPB)               // 2048 blocks
#define TOTAL_INV (1.0f / 16777216.0f)   // 1 / (B*T*C*P)

// ---------------------------------------------------------------------------
// Async global->LDS staging (width 16). LDS dest = wave-uniform base + lane*16.
// ---------------------------------------------------------------------------
typedef __attribute__((address_space(1))) const void* as1_cvoid;
typedef __attribute__((address_space(3))) void* as3_void;

__device__ __forceinline__ void stage16(const float* g, float* l) {
    __builtin_amdgcn_global_load_lds((as1_cvoid)g, (as3_void)l, 16, 0, 0);
}

__device__ __forceinline__ size_t src_of(const int* pB, const int* pT,
                                         const int* pC, int b, int t, int c) {
    return ((size_t)((pB[b] * TT + pT[t]) * CC + pC[c])) * PP;
}

// ---------------------------------------------------------------------------
// Mask-dtype classifier (16 KiB scan) — proven in round 2.
// ---------------------------------------------------------------------------
__global__ __launch_bounds__(256) void mask_classify_kernel(
    const unsigned char* __restrict__ mask, int* __restrict__ flag)
{
    __shared__ int sc1, sc3f;
    if (threadIdx.x == 0) { sc1 = 0; sc3f = 0; }
    __syncthreads();
    int c1 = 0, c3f = 0;
    const uint4* m4 = (const uint4*)mask;
    for (int i = threadIdx.x; i < 1024; i += 256) {
        const uint4 v = m4[i];
        const unsigned int w[4] = {v.x, v.y, v.z, v.w};
        #pragma unroll
        for (int j = 0; j < 4; ++j) {
            #pragma unroll
            for (int bt = 0; bt < 4; ++bt) {
                const unsigned int byte = (w[j] >> (8 * bt)) & 0xffu;
                c1  += (byte == 0x01u);
                c3f += (byte == 0x3fu);
            }
        }
    }
    atomicAdd(&sc1, c1);
    atomicAdd(&sc3f, c3f);
    __syncthreads();
    if (threadIdx.x == 0) {
        int f;
        if      (sc1  > 1000) f = 0;   // u8 bool
        else if (sc3f >  600) f = 1;   // bf16
        else if (sc3f >  200) f = 2;   // f32
        else if (sc1  >  200) f = 3;   // i32
        else                  f = 0;
        *flag = f;
    }
}

template <int MODE>
__device__ __forceinline__ void mask_load(const unsigned char* __restrict__ mask,
                                          size_t idx, float mf[4])
{
    if (MODE == 0) {
        const unsigned int mv = *(const unsigned int*)(mask + idx);
        #pragma unroll
        for (int k = 0; k < 4; ++k) mf[k] = ((mv >> (8 * k)) & 0xffu) ? 1.0f : 0.0f;
    } else if (MODE == 1) {
        const ushort4 mv = *(const ushort4*)((const unsigned short*)mask + idx);
        mf[0] = mv.x ? 1.0f : 0.0f; mf[1] = mv.y ? 1.0f : 0.0f;
        mf[2] = mv.z ? 1.0f : 0.0f; mf[3] = mv.w ? 1.0f : 0.0f;
    } else if (MODE == 2) {
        const float4 mv = *(const float4*)((const float*)mask + idx);
        mf[0] = mv.x != 0.f ? 1.0f : 0.0f; mf[1] = mv.y != 0.f ? 1.0f : 0.0f;
        mf[2] = mv.z != 0.f ? 1.0f : 0.0f; mf[3] = mv.w != 0.f ? 1.0f : 0.0f;
    } else {
        const int4 mv = *(const int4*)((const int*)mask + idx);
        mf[0] = mv.x ? 1.0f : 0.0f; mf[1] = mv.y ? 1.0f : 0.0f;
        mf[2] = mv.z ? 1.0f : 0.0f; mf[3] = mv.w ? 1.0f : 0.0f;
    }
}

// ---------------------------------------------------------------------------
// Block body: RPB rows, single 24 KB buffer, per-row {stage+stream -> sync ->
// batched gather cluster -> FMA -> sync}. Gather ds_reads are register-batched
// (issue cluster, one wait) — fenced with sched_barrier so hipcc cannot
// re-serialize them against their uses.
// ---------------------------------------------------------------------------
template <int MODE>
__device__ __forceinline__ void block_body(
    const float* __restrict__ x, const float* __restrict__ attn,
    const float* __restrict__ noise, const unsigned char* __restrict__ mask,
    const int* __restrict__ pB1, const int* __restrict__ pT1,
    const int* __restrict__ pC1, const int* __restrict__ pP1,
    const int* __restrict__ pB2, const int* __restrict__ pT2,
    const int* __restrict__ pC2, const int* __restrict__ pP2,
    const int* __restrict__ pB3, const int* __restrict__ pT3,
    const int* __restrict__ pC3, const int* __restrict__ pP3,
    float (*sbuf)[PP],
    int r0, int tid, int wave, int lane,
    float& s0, float& s1, float& s2, float& s3)
{
    #pragma unroll
    for (int i = 0; i < RPB; ++i) {
        const int r = r0 + i;
        const int b = r / (TT * CC);
        const int t = (r / CC) % TT;
        const int c = r % CC;
        const size_t a0 = src_of(pB1, pT1, pC1, b, t, c);
        const size_t a1 = src_of(pB2, pT2, pC2, b, t, c);
        const size_t a2 = src_of(pB3, pT3, pC3, b, t, c);

        // --- stage 3 source rows (6 global_load_lds / thread) ---
        #pragma unroll
        for (int s = 0; s < 2; ++s) {
            const int seg = wave + s * 4;
            const int fo  = seg * 256 + lane * 4;
            stage16(x + a0 + fo, &sbuf[0][seg * 256]);
            stage16(x + a1 + fo, &sbuf[1][seg * 256]);
            stage16(x + a2 + fo, &sbuf[2][seg * 256]);
        }

        // --- streaming loads (13 VMEM -> VGPR), all issued up front ---
        const size_t rowbase = (size_t)r * PP;
        const int p0 = tid << 2;
        const int p1 = 1024 + (tid << 2);
        const float4 xv0 = *(const float4*)(x + rowbase + p0);
        const float4 xv1 = *(const float4*)(x + rowbase + p1);
        const float4 av0 = *(const float4*)(attn + rowbase + p0);
        const float4 av1 = *(const float4*)(attn + rowbase + p1);
        const float4 nv0 = *(const float4*)(noise + rowbase + p0);
        const float4 nv1 = *(const float4*)(noise + rowbase + p1);
        const int4 q10 = *(const int4*)(pP1 + p0);
        const int4 q11 = *(const int4*)(pP1 + p1);
        const int4 q20 = *(const int4*)(pP2 + p0);
        const int4 q21 = *(const int4*)(pP2 + p1);
        const int4 q30 = *(const int4*)(pP3 + p0);
        const int4 q31 = *(const int4*)(pP3 + p1);
        float mf0[4], mf1[4];
        mask_load<MODE>(mask, rowbase + p0, mf0);
        mask_load<MODE>(mask, rowbase + p1, mf1);

        const float as0[4]  = {av0.x, av0.y, av0.z, av0.w};
        const float as1v[4] = {av1.x, av1.y, av1.z, av1.w};

        // --- pos term (overlaps staging latency) ---
        {
            const float ns0[4] = {nv0.x, nv0.y, nv0.z, nv0.w};
            const float ns1[4] = {nv1.x, nv1.y, nv1.z, nv1.w};
            #pragma unroll
            for (int k = 0; k < 4; ++k) {
                const float d0a = ns0[k] * mf0[k];
                s0 += as0[k] * d0a * d0a;
                const float d0b = ns1[k] * mf1[k];
                s0 += as1v[k] * d0b * d0b;
            }
        }

        __syncthreads();  // staging visible to all waves

        // --- batched gather cluster: 24 ds_reads issued back-to-back ---
        const int q1s[8] = {q10.x, q10.y, q10.z, q10.w, q11.x, q11.y, q11.z, q11.w};
        const int q2s[8] = {q20.x, q20.y, q20.z, q20.w, q21.x, q21.y, q21.z, q21.w};
        const int q3s[8] = {q30.x, q30.y, q30.z, q30.w, q31.x, q31.y, q31.z, q31.w};
        float g1[8], g2[8], g3[8];
        #pragma unroll
        for (int k = 0; k < 8; ++k) g1[k] = sbuf[0][q1s[k]];
        #pragma unroll
        for (int k = 0; k < 8; ++k) g2[k] = sbuf[1][q2s[k]];
        #pragma unroll
        for (int k = 0; k < 8; ++k) g3[k] = sbuf[2][q3s[k]];
        __builtin_amdgcn_sched_barrier(0);  // pin: loads above, math below

        // --- pure-VALU neg terms ---
        {
            const float xs[8] = {xv0.x, xv0.y, xv0.z, xv0.w,
                                 xv1.x, xv1.y, xv1.z, xv1.w};
            const float aa[8] = {as0[0], as0[1], as0[2], as0[3],
                                 as1v[0], as1v[1], as1v[2], as1v[3]};
            #pragma unroll
            for (int k = 0; k < 8; ++k) {
                const float d1 = xs[k] - g1[k];
                s1 += aa[k] * d1 * d1;
                const float d2 = xs[k] - g2[k];
                s2 += aa[k] * d2 * d2;
                const float d3 = xs[k] - g3[k];
                s3 += aa[k] * d3 * d3;
            }
        }

        __syncthreads();  // protect buffer before next row's staging
    }
}

__global__ __launch_bounds__(256) void attn_loss_row_kernel(
    const float* __restrict__ x, const float* __restrict__ attn,
    const float* __restrict__ noise, const unsigned char* __restrict__ mask,
    const int* __restrict__ pB1, const int* __restrict__ pT1,
    const int* __restrict__ pC1, const int* __restrict__ pP1,
    const int* __restrict__ pB2, const int* __restrict__ pT2,
    const int* __restrict__ pC2, const int* __restrict__ pP2,
    const int* __restrict__ pB3, const int* __restrict__ pT3,
    const int* __restrict__ pC3, const int* __restrict__ pP3,
    const int* __restrict__ mask_flag,
    float4* __restrict__ partial)
{
    __shared__ float sbuf[3][PP];   // 24 KiB, single-buffered
    __shared__ float red[4][4];

    const int tid  = threadIdx.x;
    const int wave = tid >> 6;
    const int lane = tid & 63;
    const int r0   = blockIdx.x * RPB;

    float s0 = 0.f, s1 = 0.f, s2 = 0.f, s3 = 0.f;

    const int f = *mask_flag;  // grid-uniform
    switch (f) {
        case 1:  block_body<1>(x, attn, noise, mask, pB1, pT1, pC1, pP1,
                               pB2, pT2, pC2, pP2, pB3, pT3, pC3, pP3,
                               sbuf, r0, tid, wave, lane, s0, s1, s2, s3); break;
        case 2:  block_body<2>(x, attn, noise, mask, pB1, pT1, pC1, pP1,
                               pB2, pT2, pC2, pP2, pB3, pT3, pC3, pP3,
                               sbuf, r0, tid, wave, lane, s0, s1, s2, s3); break;
        case 3:  block_body<3>(x, attn, noise, mask, pB1, pT1, pC1, pP1,
                               pB2, pT2, pC2, pP2, pB3, pT3, pC3, pP3,
                               sbuf, r0, tid, wave, lane, s0, s1, s2, s3); break;
        default: block_body<0>(x, attn, noise, mask, pB1, pT1, pC1, pP1,
                               pB2, pT2, pC2, pP2, pB3, pT3, pC3, pP3,
                               sbuf, r0, tid, wave, lane, s0, s1, s2, s3); break;
    }

    #pragma unroll
    for (int off = 32; off; off >>= 1) {
        s0 += __shfl_down(s0, off, 64);
        s1 += __shfl_down(s1, off, 64);
        s2 += __shfl_down(s2, off, 64);
        s3 += __shfl_down(s3, off, 64);
    }
    if (lane == 0) {
        red[0][wave] = s0; red[1][wave] = s1;
        red[2][wave] = s2; red[3][wave] = s3;
    }
    __syncthreads();
    if (tid == 0) {
        float4 out;
        out.x = red[0][0] + red[0][1] + red[0][2] + red[0][3];
        out.y = red[1][0] + red[1][1] + red[1][2] + red[1][3];
        out.z = red[2][0] + red[2][1] + red[2][2] + red[2][3];
        out.w = red[3][0] + red[3][1] + red[3][2] + red[3][3];
        partial[blockIdx.x] = out;
    }
}

__global__ __launch_bounds__(1024) void attn_loss_final_kernel(
    const float4* __restrict__ partial, float* __restrict__ out)
{
    const int tid = threadIdx.x;
    float s0 = 0.f, s1 = 0.f, s2 = 0.f, s3 = 0.f;
    for (int i = tid; i < NBLK; i += 1024) {
        const float4 v = partial[i];
        s0 += v.x; s1 += v.y; s2 += v.z; s3 += v.w;
    }
    #pragma unroll
    for (int off = 32; off; off >>= 1) {
        s0 += __shfl_down(s0, off, 64);
        s1 += __shfl_down(s1, off, 64);
        s2 += __shfl_down(s2, off, 64);
        s3 += __shfl_down(s3, off, 64);
    }
    __shared__ float red[4][16];
    const int wave = tid >> 6;
    const int lane = tid & 63;
    if (lane == 0) {
        red[0][wave] = s0; red[1][wave] = s1;
        red[2][wave] = s2; red[3][wave] = s3;
    }
    __syncthreads();
    if (tid == 0) {
        float lp = 0.f, l1 = 0.f, l2 = 0.f, l3 = 0.f;
        #pragma unroll
        for (int w = 0; w < 16; ++w) {
            lp += red[0][w]; l1 += red[1][w];
            l2 += red[2][w]; l3 += red[3][w];
        }
        lp *= TOTAL_INV; l1 *= TOTAL_INV; l2 *= TOTAL_INV; l3 *= TOTAL_INV;
        const float m   = fmaxf(l1, fmaxf(l2, l3));
        const float lse = m + logf(expf(l1 - m) + expf(l2 - m) + expf(l3 - m));
        out[0] = lse - lp;
    }
}

extern "C" void kernel_launch(void* const* d_in, const int* in_sizes, int n_in,
                              void* d_out, int out_size, void* d_ws, size_t ws_size,
                              hipStream_t stream) {
    const float* x            = (const float*)d_in[0];
    const float* attn         = (const float*)d_in[1];
    const float* noise        = (const float*)d_in[2];
    const unsigned char* mask = (const unsigned char*)d_in[3];
    const int* pB1 = (const int*)d_in[4];
    const int* pT1 = (const int*)d_in[5];
    const int* pC1 = (const int*)d_in[6];
    const int* pP1 = (const int*)d_in[7];
    const int* pB2 = (const int*)d_in[8];
    const int* pT2 = (const int*)d_in[9];
    const int* pC2 = (const int*)d_in[10];
    const int* pP2 = (const int*)d_in[11];
    const int* pB3 = (const int*)d_in[12];
    const int* pT3 = (const int*)d_in[13];
    const int* pC3 = (const int*)d_in[14];
    const int* pP3 = (const int*)d_in[15];

    float4* partial = (float4*)d_ws;                    // 32 KiB
    int* mask_flag  = (int*)((char*)d_ws + NBLK * 16);  // 4 B after partials

    mask_classify_kernel<<<1, 256, 0, stream>>>(mask, mask_flag);
    attn_loss_row_kernel<<<NBLK, 256, 0, stream>>>(
        x, attn, noise, mask,
        pB1, pT1, pC1, pP1, pB2, pT2, pC2, pP2, pB3, pT3, pC3, pP3,
        mask_flag, partial);
    attn_loss_final_kernel<<<1, 1024, 0, stream>>>(partial, (float*)d_out);
}